// Round 10
// baseline (510.127 us; speedup 1.0000x reference)
//
#include <hip/hip_runtime.h>
#include <math.h>

// ---- problem constants ----
#define NT   16384
#define HD   4096
#define NE   64
#define TOPK 8

// ---- d_out layout: FLOAT32 elements (proven rounds 5/7/8/9) ----
#define L_OFF 0
#define W_OFF (NT * NE)                  // 1048576
#define I_OFF (W_OFF + NT * TOPK)        // 1179648
#define M_OFF (I_OFF + NT * TOPK)        // 1310720 ; mask = NE*TOPK*NT floats

#define BK 64                            // K-chunk
#define XS_STRIDE 65                     // 2-way only (free) for both write and read patterns

typedef __attribute__((ext_vector_type(4))) float f4;

// ---- kernel A: zero the fp32 mask region ----
__global__ __launch_bounds__(256) void kz_mask(f4* __restrict__ p, int n4) {
  f4 z = {0.f, 0.f, 0.f, 0.f};
  for (int i = blockIdx.x * 256 + threadIdx.x; i < n4; i += gridDim.x * 256) p[i] = z;
}

// ---- kernel B: fp32 VALU GEMM; lane=token, w via wave-uniform scalar loads ----
// block 512 thr (8 waves) = tile 64 tokens x 64 experts; wave wv: experts wv*8..+7.
// x: LDS double-buffered (only per-lane LDS traffic: 1 ds_read_b128 / 32 fma).
// w: read directly from global with wave-uniform addresses -> SMEM (s_load) pipe.
// Per-(t,e) accumulation BITWISE-IDENTICAL to rounds 5-9: 4 component chains
// (k mod 4), k ascending, final ((c0+c1)+c2)+c3 + bias.
__global__ __launch_bounds__(512, 2) void k_gemm(const float* __restrict__ x,
                                                 const float* __restrict__ w,
                                                 const float* __restrict__ bias,
                                                 float* __restrict__ out) {
  __shared__ float xs0[64 * XS_STRIDE];  // 16.6 KB
  __shared__ float xs1[64 * XS_STRIDE];  // 16.6 KB

  const int tid  = threadIdx.x;
  const int lane = tid & 63;                                   // token within tile
  const int wvu  = __builtin_amdgcn_readfirstlane(tid >> 6);   // wave id 0..7 (SGPR)
  const int e0   = wvu * 8;                                    // this wave's experts
  const int tok0 = blockIdx.x * 64;

  f4 acc[8];
#pragma unroll
  for (int s = 0; s < 8; ++s) acc[s] = (f4){0.f, 0.f, 0.f, 0.f};

  // staging ownership: 1024 f4-units/chunk, 512 thr -> units tid and tid+512
  const int r0 = tid >> 4;               // rows 0..31
  const int su = tid & 15;
  const int r1 = r0 + 32;                // rows 32..63
  const float* xb0 = x + (size_t)(tok0 + r0) * HD + su * 4;
  const float* xb1 = x + (size_t)(tok0 + r1) * HD + su * 4;

  // prologue: chunk0 -> LDS(cur); chunk1 -> regs
  f4 xr0 = *(const f4*)(xb0);
  f4 xr1 = *(const f4*)(xb1);
  float* cur = xs0;
  float* nxt = xs1;
  *(f4*)(cur + r0 * XS_STRIDE + su * 4) = xr0;
  *(f4*)(cur + r1 * XS_STRIDE + su * 4) = xr1;
  xr0 = *(const f4*)(xb0 + BK);
  xr1 = *(const f4*)(xb1 + BK);
  __syncthreads();

  for (int c = 0; c < HD / BK; ++c) {
    // stage chunk c+1 (regs already landed) into the other buffer
    if (c + 1 < HD / BK) {
      *(f4*)(nxt + r0 * XS_STRIDE + su * 4) = xr0;
      *(f4*)(nxt + r1 * XS_STRIDE + su * 4) = xr1;
    }
    // issue chunk c+2 global loads; they complete under this chunk's compute
    if (c + 2 < HD / BK) {
      xr0 = *(const f4*)(xb0 + (c + 2) * BK);
      xr1 = *(const f4*)(xb1 + (c + 2) * BK);
    }

    // compute chunk c: per st, 1 per-lane LDS b128 (x) + 8 uniform s_load (w) + 32 fma
    const float* wc = w + c * BK;        // uniform
#pragma unroll
    for (int st = 0; st < 16; ++st) {
      const int k0 = st * 4;
      f4 xv = *(const f4*)(cur + lane * XS_STRIDE + k0);
#pragma unroll
      for (int s = 0; s < 8; ++s) {
        f4 wf = *(const f4*)(wc + (size_t)(e0 + s) * HD + k0);   // wave-uniform -> SMEM
        acc[s][0] = fmaf(xv[0], wf[0], acc[s][0]);
        acc[s][1] = fmaf(xv[1], wf[1], acc[s][1]);
        acc[s][2] = fmaf(xv[2], wf[2], acc[s][2]);
        acc[s][3] = fmaf(xv[3], wf[3], acc[s][3]);
      }
    }
    __syncthreads();
    float* t = cur; cur = nxt; nxt = t;
  }

  // epilogue: same final-sum order as rounds 5-9; experts e0..e0+7 are consecutive
  float res[8];
#pragma unroll
  for (int s = 0; s < 8; ++s)
    res[s] = acc[s][0] + acc[s][1] + acc[s][2] + acc[s][3] + bias[e0 + s];
  float* dst = out + L_OFF + (size_t)(tok0 + lane) * NE + e0;
  *(f4*)(dst)     = (f4){res[0], res[1], res[2], res[3]};
  *(f4*)(dst + 4) = (f4){res[4], res[5], res[6], res[7]};
}

// ---- kernel C: top-8 from stored fp32 logits (rounds 5-9 verbatim selection) ----
__global__ __launch_bounds__(256) void k_topk(float* __restrict__ out) {
  const int lane = threadIdx.x & 63;            // lane == expert
  const int wv   = threadIdx.x >> 6;
  const int t    = blockIdx.x * 4 + wv;

  float v = out[L_OFF + (size_t)t * NE + lane];

  // rank = #{e : v_e > v or (v_e == v and e < lane)}  (stable, lax.top_k order)
  int rank = 0;
  for (int e = 0; e < NE; ++e) {
    float ve = __shfl(v, e);
    rank += (ve > v) || (ve == v && e < lane);
  }

  // weights = softmax over the selected 8 (global Z cancels in renormalization)
  float m0 = v;
#pragma unroll
  for (int o = 32; o; o >>= 1) m0 = fmaxf(m0, __shfl_xor(m0, o));
  float ev = (rank < TOPK) ? expf(v - m0) : 0.f;
  float s = ev;
#pragma unroll
  for (int o = 32; o; o >>= 1) s += __shfl_xor(s, o);

  if (rank < TOPK) {
    out[W_OFF + (size_t)t * TOPK + rank] = ev / s;
    out[I_OFF + (size_t)t * TOPK + rank] = (float)lane;                  // exact (<=63)
    out[M_OFF + ((size_t)lane * TOPK + rank) * NT + t] = 1.0f;           // mask one-hot
  }
}

extern "C" void kernel_launch(void* const* d_in, const int* in_sizes, int n_in,
                              void* d_out, int out_size, void* d_ws, size_t ws_size,
                              hipStream_t stream) {
  const float* x  = (const float*)d_in[0];
  const float* gw = (const float*)d_in[1];
  const float* gb = (const float*)d_in[2];
  float* out = (float*)d_out;

  kz_mask<<<2048, 256, 0, stream>>>((f4*)(out + M_OFF), (NE * TOPK * NT) / 4);
  k_gemm <<<NT / 64, 512, 0, stream>>>(x, gw, gb, out);
  k_topk <<<NT / 4, 256, 0, stream>>>(out);
}